// Round 4
// baseline (1048.134 us; speedup 1.0000x reference)
//
#include <hip/hip_runtime.h>

#define NB 128
#define NP 576
#define NK 9
#define EMB 768
#define SGRID 24
#define COMPF 3.0f
#define NITER 10
#define EPSV 1e-8f
#define NT 6     // tiles per item
#define TP 96    // points per tile
#define BT 384   // threads per block (6 waves)

typedef short v8s __attribute__((ext_vector_type(8)));
typedef float v4f __attribute__((ext_vector_type(4)));

__device__ __forceinline__ unsigned short f2b(float f) {
    unsigned x = __float_as_uint(f);
    unsigned r = (x + 0x7fffu + ((x >> 16) & 1u)) >> 16;
    return (unsigned short)r;
}
__device__ __forceinline__ float b2f(unsigned short u) {
    return __uint_as_float(((unsigned)u) << 16);
}

// ---------------- init: fp32->bf16 conversion + indicator partials ----------
// grid NB*NT, BT thr. Tile pb = 4 grid-rows (single seed band ay = pb/2).
// Thread t owns channels 2t,2t+1. Accumulates fp32 sums (matches ref pooling).
__global__ __launch_bounds__(BT) void init_k(const float* __restrict__ emb,
                                             unsigned short* __restrict__ embb,
                                             unsigned short* __restrict__ pcent,
                                             float* __restrict__ pmeta) {
    int blk = blockIdx.x, b = blk / NT, pb = blk % NT;
    int t = threadIdx.x;
    int ay = pb >> 1;

    const float* eg = emb + (size_t)(b * NP + pb * TP) * EMB + 2 * t;
    unsigned short* og = embb + (size_t)(b * NP + pb * TP) * EMB + 2 * t;
    float a0x=0,a0y=0, a1x=0,a1y=0, a2x=0,a2y=0;
    for (int lp = 0; lp < TP; ++lp) {
        float2 f = *(const float2*)(eg + (size_t)lp * EMB);
        ushort2 u; u.x = f2b(f.x); u.y = f2b(f.y);
        *(ushort2*)(og + (size_t)lp * EMB) = u;
        int ax = (lp % SGRID) >> 3;   // block-uniform per lp
        if (ax == 0)      { a0x += f.x; a0y += f.y; }
        else if (ax == 1) { a1x += f.x; a1y += f.y; }
        else              { a2x += f.x; a2y += f.y; }
    }
    unsigned short* pc = pcent + (size_t)(b * NT + pb) * NK * EMB + 2 * t;
    #pragma unroll
    for (int k = 0; k < NK; ++k) {
        int s = k - ay * 3;
        float vx = 0.f, vy = 0.f;
        if (s == 0)      { vx = a0x; vy = a0y; }
        else if (s == 1) { vx = a1x; vy = a1y; }
        else if (s == 2) { vx = a2x; vy = a2y; }
        ushort2 u; u.x = f2b(vx); u.y = f2b(vy);
        *(ushort2*)(pc + (size_t)k * EMB) = u;
    }
    if (t < NK) {
        int ky = t / 3, kx = t % 3;
        float w = 0.f, sx = 0.f, sy = 0.f;
        if (ky == ay) {
            w = 32.f;
            sx = 12.f * (64.f * kx + 28.f);   // 4 rows * sum(3x), x in [8kx,8kx+8)
            sy = 24.f * (16.f * pb + 6.f);    // 8 cols * sum(3y), y in [4pb,4pb+4)
        }
        *(float4*)(pmeta + ((size_t)(b * NT + pb) * NK + t) * 4) =
            make_float4(w, sx, sy, 0.f);
    }
}

// ---------------- fused: reduce-prologue + MFMA assign + WTA update ---------
// grid NB*NT, BT thr (6 waves). Wave wv owns rows pb*96 + wv*16 .. +15.
__global__ __launch_bounds__(BT) void fused_k(
    const unsigned short* __restrict__ embb,
    const unsigned short* __restrict__ pcin,   // [NB][NT][NK][768] bf16
    const float* __restrict__ pmin,            // [NB][NT][NK][4] {w,sx,sy,_}
    unsigned short* __restrict__ pcout,
    float* __restrict__ pmout,
    float* __restrict__ out, int outMode)
{
    __shared__ unsigned short sc[16][776];   // centroids bf16 (pad: 2-way banks)
    __shared__ float sw[NK], scx[16], scy[16], sc2[16];
    __shared__ float red[6][3][16];
    __shared__ int swin[TP];

    int blk = blockIdx.x, b = blk / NT, pb = blk % NT;
    int t = threadIdx.x, lane = t & 63, wv = t / 64;
    int r16 = lane & 15, g = lane >> 4;

    // (a) meta: w, spatial centroids
    if (t < NK) {
        float w = 0.f, sx = 0.f, sy = 0.f;
        for (int s = 0; s < NT; ++s) {
            float4 q = *(const float4*)(pmin + ((size_t)(b * NT + s) * NK + t) * 4);
            w += q.x; sx += q.y; sy += q.z;
        }
        float wi = w + EPSV;
        sw[t] = wi; scx[t] = sx / wi; scy[t] = sy / wi;
    }
    if (t >= NK && t < 16) { scx[t] = 0.f; scy[t] = 0.f; }
    // zero-pad clusters 9..15
    for (int i = t; i < 7 * 96; i += BT) {
        int k = 9 + i / 96, s8 = i % 96;
        v8s z = {0,0,0,0,0,0,0,0};
        *(v8s*)&sc[k][s8 * 8] = z;
    }
    __syncthreads();

    // (b) centroid channels: thread t owns channels 2t,2t+1 for every k
    float c2p[NK];
    #pragma unroll
    for (int k = 0; k < NK; ++k) {
        float s0 = 0.f, s1 = 0.f;
        for (int s = 0; s < NT; ++s) {
            ushort2 u = *(const ushort2*)(pcin + ((size_t)(b * NT + s) * NK + k) * EMB + 2 * t);
            s0 += b2f(u.x); s1 += b2f(u.y);
        }
        float r0 = s0 / sw[k], r1 = s1 / sw[k];
        ushort2 u2; u2.x = f2b(r0); u2.y = f2b(r1);
        *(ushort2*)&sc[k][2 * t] = u2;
        c2p[k] = r0 * r0 + r1 * r1;
    }
    #pragma unroll
    for (int k = 0; k < NK; ++k) {
        float s = c2p[k];
        #pragma unroll
        for (int m = 1; m < 64; m <<= 1) s += __shfl_xor(s, m);
        if (lane == 0) red[wv][0][k] = s;
    }
    __syncthreads();
    if (t < NK) {
        float s = red[0][0][t] + red[1][0][t] + red[2][0][t] +
                  red[3][0][t] + red[4][0][t] + red[5][0][t];
        sc2[t] = s + scx[t] * scx[t] + scy[t] * scy[t];
    }
    if (t >= NK && t < 16) sc2[t] = 1e30f;
    __syncthreads();

    // phase 1: logits via MFMA, A-fragments direct from global
    int row = pb * TP + wv * 16 + r16;
    const unsigned short* ap = embb + ((size_t)b * NP + row) * EMB + g * 8;
    v4f acc = {0.f, 0.f, 0.f, 0.f};
    #pragma unroll
    for (int cn = 0; cn < 12; ++cn) {
        #pragma unroll
        for (int ks = 0; ks < 2; ++ks) {
            v8s af = *(const v8s*)(ap + cn * 64 + ks * 32);
            v8s bf = *(const v8s*)&sc[r16][cn * 64 + ks * 32 + g * 8];
            acc = __builtin_amdgcn_mfma_f32_16x16x32_bf16(af, bf, acc, 0, 0, 0);
        }
    }

    // epilogue: C/D layout col=r16, row=g*4+j
    float cxv = scx[r16], cyv = scy[r16], c2v = sc2[r16];
    float wsum = 0.f, sxsum = 0.f, sysum = 0.f;
    #pragma unroll
    for (int j = 0; j < 4; ++j) {
        int lr = wv * 16 + g * 4 + j;
        int p = pb * TP + lr;
        float px = (float)(p % SGRID) * COMPF;
        float py = (float)(p / SGRID) * COMPF;
        float lg = 2.f * (acc[j] + px * cxv + py * cyv) - c2v;
        if (outMode) {
            float mx = lg;
            mx = fmaxf(mx, __shfl_xor(mx, 1));
            mx = fmaxf(mx, __shfl_xor(mx, 2));
            mx = fmaxf(mx, __shfl_xor(mx, 4));
            mx = fmaxf(mx, __shfl_xor(mx, 8));
            float e = __expf(lg - mx);
            float se = e;
            se += __shfl_xor(se, 1);
            se += __shfl_xor(se, 2);
            se += __shfl_xor(se, 4);
            se += __shfl_xor(se, 8);
            if (r16 < NK) out[((size_t)b * NP + p) * NK + r16] = e / se;
        } else {
            float m = lg; int ki = r16;
            #pragma unroll
            for (int d = 1; d < 16; d <<= 1) {
                float om = __shfl_xor(m, d);
                int oi = __shfl_xor(ki, d);
                if (om > m || (om == m && oi < ki)) { m = om; ki = oi; }
            }
            if (r16 == 0) swin[lr] = ki;
            float hit = (ki == r16) ? 1.f : 0.f;
            wsum += hit; sxsum += hit * px; sysum += hit * py;
        }
    }
    if (outMode) return;

    wsum  += __shfl_xor(wsum, 16);  wsum  += __shfl_xor(wsum, 32);
    sxsum += __shfl_xor(sxsum, 16); sxsum += __shfl_xor(sxsum, 32);
    sysum += __shfl_xor(sysum, 16); sysum += __shfl_xor(sysum, 32);
    if (lane < 16) {
        red[wv][0][r16] = wsum;
        red[wv][1][r16] = sxsum;
        red[wv][2][r16] = sysum;
    }
    __syncthreads();

    if (t < NK) {
        float w  = red[0][0][t] + red[1][0][t] + red[2][0][t] + red[3][0][t] + red[4][0][t] + red[5][0][t];
        float sx = red[0][1][t] + red[1][1][t] + red[2][1][t] + red[3][1][t] + red[4][1][t] + red[5][1][t];
        float sy = red[0][2][t] + red[1][2][t] + red[2][2][t] + red[3][2][t] + red[4][2][t] + red[5][2][t];
        *(float4*)(pmout + ((size_t)(b * NT + pb) * NK + t) * 4) =
            make_float4(w, sx, sy, 0.f);
    }

    // phase 2: WTA partial sums; thread t owns channels 2t,2t+1
    float pa[NK][2];
    #pragma unroll
    for (int k = 0; k < NK; ++k) { pa[k][0] = 0.f; pa[k][1] = 0.f; }
    const unsigned short* e2 = embb + ((size_t)b * NP + pb * TP) * EMB + 2 * t;
    for (int lp = 0; lp < TP; ++lp) {
        int kw = __builtin_amdgcn_readfirstlane(swin[lp]);
        ushort2 u = *(const ushort2*)(e2 + (size_t)lp * EMB);
        float f0 = b2f(u.x), f1 = b2f(u.y);
        switch (kw) {
            case 0: pa[0][0] += f0; pa[0][1] += f1; break;
            case 1: pa[1][0] += f0; pa[1][1] += f1; break;
            case 2: pa[2][0] += f0; pa[2][1] += f1; break;
            case 3: pa[3][0] += f0; pa[3][1] += f1; break;
            case 4: pa[4][0] += f0; pa[4][1] += f1; break;
            case 5: pa[5][0] += f0; pa[5][1] += f1; break;
            case 6: pa[6][0] += f0; pa[6][1] += f1; break;
            case 7: pa[7][0] += f0; pa[7][1] += f1; break;
            default: pa[8][0] += f0; pa[8][1] += f1; break;
        }
    }
    unsigned short* po = pcout + (size_t)(b * NT + pb) * NK * EMB + 2 * t;
    #pragma unroll
    for (int k = 0; k < NK; ++k) {
        ushort2 u; u.x = f2b(pa[k][0]); u.y = f2b(pa[k][1]);
        *(ushort2*)(po + (size_t)k * EMB) = u;
    }
}

extern "C" void kernel_launch(void* const* d_in, const int* in_sizes, int n_in,
                              void* d_out, int out_size, void* d_ws, size_t ws_size,
                              hipStream_t stream) {
    const float* emb = (const float*)d_in[0];
    char* w = (char*)d_ws;
    unsigned short* embb = (unsigned short*)w; w += (size_t)NB * NP * EMB * 2;        // 113.2 MB
    unsigned short* pcA = (unsigned short*)w;  w += (size_t)NB * NT * NK * EMB * 2;   // 10.6 MB
    unsigned short* pcB = (unsigned short*)w;  w += (size_t)NB * NT * NK * EMB * 2;   // 10.6 MB
    float* pmA = (float*)w;                    w += (size_t)NB * NT * NK * 4 * 4;
    float* pmB = (float*)w;                    w += (size_t)NB * NT * NK * 4 * 4;

    init_k<<<NB * NT, BT, 0, stream>>>(emb, embb, pcA, pmA);

    unsigned short *ci = pcA, *co = pcB;
    float *mi = pmA, *mo = pmB;
    for (int it = 0; it < NITER; ++it) {
        fused_k<<<NB * NT, BT, 0, stream>>>(embb, ci, mi, co, mo, nullptr, 0);
        unsigned short* tc = ci; ci = co; co = tc;
        float* tm = mi; mi = mo; mo = tm;
    }
    fused_k<<<NB * NT, BT, 0, stream>>>(embb, ci, mi, co, mo, (float*)d_out, 1);
}

// Round 5
// 743.109 us; speedup vs baseline: 1.4105x; 1.4105x over previous
//
#include <hip/hip_runtime.h>

#define NB 128
#define NP 576
#define NK 9
#define EMB 768
#define SGRID 24
#define COMPF 3.0f
#define NITER 10
#define EPSV 1e-8f
#define CSTR 772   // per-cluster stride in pcent: 768 ch + sx,sy,w,pad

typedef short v8s __attribute__((ext_vector_type(8)));
typedef float v4f __attribute__((ext_vector_type(4)));

__device__ __forceinline__ unsigned short f2b(float f) {
    unsigned x = __float_as_uint(f);
    unsigned r = (x + 0x7fffu + ((x >> 16) & 1u)) >> 16;
    return (unsigned short)r;
}
__device__ __forceinline__ float b2f(unsigned short u) {
    return __uint_as_float(((unsigned)u) << 16);
}

// ---------------- init: fp32->bf16 conversion + indicator partials ----------
// grid NB*9, 192 thr. Block = one 64-point tile; ay = pb/3 (3 tiles per band).
__global__ __launch_bounds__(192) void init_k(const float* __restrict__ emb,
                                              unsigned short* __restrict__ embb,
                                              float* __restrict__ pcent) {
    int blk = blockIdx.x, b = blk / 9, pb = blk % 9;
    int t = threadIdx.x;
    int ay = pb / 3;

    float a0x=0,a0y=0,a0z=0,a0w=0, a1x=0,a1y=0,a1z=0,a1w=0, a2x=0,a2y=0,a2z=0,a2w=0;
    const float* eg = emb + ((size_t)b * NP + pb * 64) * EMB + t * 4;
    unsigned short* og = embb + ((size_t)b * NP + pb * 64) * EMB + t * 4;
    for (int p = 0; p < 64; ++p) {
        float4 f = *(const float4*)(eg + (size_t)p * EMB);
        ushort4 u;
        u.x = f2b(f.x); u.y = f2b(f.y); u.z = f2b(f.z); u.w = f2b(f.w);
        *(ushort4*)(og + (size_t)p * EMB) = u;
        int pg = pb * 64 + p;
        int sel = (pg % SGRID) >> 3;   // 0..2
        bool m0 = (sel == 0), m1 = (sel == 1), m2 = (sel == 2);
        a0x += m0 ? f.x : 0.f; a0y += m0 ? f.y : 0.f; a0z += m0 ? f.z : 0.f; a0w += m0 ? f.w : 0.f;
        a1x += m1 ? f.x : 0.f; a1y += m1 ? f.y : 0.f; a1z += m1 ? f.z : 0.f; a1w += m1 ? f.w : 0.f;
        a2x += m2 ? f.x : 0.f; a2y += m2 ? f.y : 0.f; a2z += m2 ? f.z : 0.f; a2w += m2 ? f.w : 0.f;
    }
    float* pc = pcent + (size_t)(b * 9 + pb) * NK * CSTR;
    #pragma unroll
    for (int k = 0; k < NK; ++k) {
        int s = k - ay * 3;
        float4 v = make_float4(0.f, 0.f, 0.f, 0.f);
        if (s == 0) v = make_float4(a0x, a0y, a0z, a0w);
        if (s == 1) v = make_float4(a1x, a1y, a1z, a1w);
        if (s == 2) v = make_float4(a2x, a2y, a2z, a2w);
        *(float4*)&pc[k * CSTR + t * 4] = v;
    }
    if (t < NK) {
        int s = t - ay * 3;
        float w = 0.f, sx = 0.f, sy = 0.f;
        if (s >= 0 && s < 3) {
            for (int p = 0; p < 64; ++p) {
                int pg = pb * 64 + p;
                if (((pg % SGRID) >> 3) == s) {
                    w += 1.f;
                    sx += (float)(pg % SGRID) * COMPF;
                    sy += (float)(pg / SGRID) * COMPF;
                }
            }
        }
        pc[t * CSTR + 768] = sx; pc[t * CSTR + 769] = sy; pc[t * CSTR + 770] = w;
    }
}

// ---------------- fused: MFMA assign + WTA-list partial update ----------------
// grid NB*9, 256 thr (4 waves). Phase 1: round-3 LDS-staged double-buffered
// MFMA. Epilogue: argmax (iter mode) / softmax (out mode). Phase 2: per-cluster
// point lists (ballot-built), branch-free accumulation, static acc indexing.
__global__ __launch_bounds__(256) void fused_k(
    const unsigned short* __restrict__ embb,   // [NB][576][768] bf16
    const unsigned short* __restrict__ centb,  // [NB][9][768] bf16
    const float* __restrict__ csp,             // [NB][9][2]
    float* __restrict__ pcent,                 // [NB][9][NK][CSTR]
    float* __restrict__ out, int outMode)
{
    __shared__ unsigned short sc[16][776];     // B: [cluster][768 + pad8]
    __shared__ unsigned short sa[2][64][64];   // A dbuf, slice-swizzled
    __shared__ float scx[16], scy[16], sc2[16];
    __shared__ int swin[64];
    __shared__ int scnt[NK];
    __shared__ unsigned char splist[NK][64];

    int blk = blockIdx.x;
    int b = blk / 9, pb = blk % 9;
    int t = threadIdx.x, lane = t & 63, wv = t >> 6;
    int r16 = lane & 15, g = lane >> 4;

    // stage centroids (B operand), zero-pad clusters 9..15
    const unsigned short* cg = centb + (size_t)b * NK * EMB;
    for (int i = t; i < NK * 96; i += 256) {
        int k = i / 96, s = i % 96;
        *(v8s*)&sc[k][s * 8] = *(const v8s*)&cg[k * EMB + s * 8];
    }
    for (int i = t; i < 7 * 96; i += 256) {
        int k = 9 + i / 96, s = i % 96;
        v8s z = {0,0,0,0,0,0,0,0};
        *(v8s*)&sc[k][s * 8] = z;
    }
    if (t < 16) {
        scx[t] = (t < NK) ? csp[((size_t)b * NK + t) * 2 + 0] : 0.f;
        scy[t] = (t < NK) ? csp[((size_t)b * NK + t) * 2 + 1] : 0.f;
    }

    // first A chunk (issue before the barrier; stored after)
    const unsigned short* eg = embb + ((size_t)b * NP + pb * 64) * EMB;
    int srow = wv * 16 + (lane >> 3);
    int sphys = ((lane & 7) ^ (lane >> 3)) * 8;
    const unsigned short* gbase = eg + (size_t)srow * EMB + (lane & 7) * 8;
    v8s st0 = *(const v8s*)(gbase);
    v8s st1 = *(const v8s*)(gbase + 8 * EMB);

    __syncthreads();   // sc, scx/scy ready

    // c2 from staged bf16 centroids — wave 0
    if (wv == 0) {
        for (int k = 0; k < NK; ++k) {
            float s = 0.f;
            const unsigned short* ck = sc[k];
            for (int c = lane; c < EMB; c += 64) { float v = b2f(ck[c]); s += v * v; }
            #pragma unroll
            for (int m = 1; m < 64; m <<= 1) s += __shfl_xor(s, m);
            if (lane == 0) sc2[k] = s + scx[k] * scx[k] + scy[k] * scy[k];
        }
        if (lane >= NK && lane < 16) sc2[lane] = 1e30f;
    }

    *(v8s*)&sa[0][srow][sphys] = st0;
    *(v8s*)&sa[0][srow + 8][sphys] = st1;

    v4f acc = {0.f, 0.f, 0.f, 0.f};
    for (int cn = 0; cn < 12; ++cn) {
        v8s n0, n1;
        if (cn < 11) {
            n0 = *(const v8s*)(gbase + (cn + 1) * 64);
            n1 = *(const v8s*)(gbase + (cn + 1) * 64 + 8 * EMB);
        }
        __syncthreads();
        int cur = cn & 1;
        #pragma unroll
        for (int ks = 0; ks < 2; ++ks) {
            v8s af = *(const v8s*)&sa[cur][wv * 16 + r16][(((ks << 2) + g) ^ (r16 & 7)) << 3];
            v8s bf = *(const v8s*)&sc[r16][cn * 64 + ks * 32 + g * 8];
            acc = __builtin_amdgcn_mfma_f32_16x16x32_bf16(af, bf, acc, 0, 0, 0);
        }
        if (cn < 11) {
            *(v8s*)&sa[cur ^ 1][srow][sphys] = n0;
            *(v8s*)&sa[cur ^ 1][srow + 8][sphys] = n1;
        }
    }

    // epilogue: C/D layout col=r16, row=g*4+j
    float cxv = scx[r16], cyv = scy[r16], c2v = sc2[r16];
    #pragma unroll
    for (int j = 0; j < 4; ++j) {
        int lr = wv * 16 + g * 4 + j;
        int p = pb * 64 + lr;
        float px = (float)(p % SGRID) * COMPF;
        float py = (float)(p / SGRID) * COMPF;
        float lg = 2.f * (acc[j] + px * cxv + py * cyv) - c2v;
        if (outMode) {
            float mx = lg;
            mx = fmaxf(mx, __shfl_xor(mx, 1));
            mx = fmaxf(mx, __shfl_xor(mx, 2));
            mx = fmaxf(mx, __shfl_xor(mx, 4));
            mx = fmaxf(mx, __shfl_xor(mx, 8));
            float e = __expf(lg - mx);
            float se = e;
            se += __shfl_xor(se, 1);
            se += __shfl_xor(se, 2);
            se += __shfl_xor(se, 4);
            se += __shfl_xor(se, 8);
            if (r16 < NK) out[((size_t)b * NP + p) * NK + r16] = e / se;
        } else {
            float m = lg; int ki = r16;
            #pragma unroll
            for (int d = 1; d < 16; d <<= 1) {
                float om = __shfl_xor(m, d);
                int oi = __shfl_xor(ki, d);
                if (om > m || (om == m && oi < ki)) { m = om; ki = oi; }
            }
            if (r16 == 0) swin[lr] = ki;
        }
    }
    if (outMode) return;
    __syncthreads();   // swin complete

    // build per-cluster lists: wave wv handles clusters wv, wv+4, wv+8
    {
        int myk = swin[lane];
        for (int kk = wv; kk < NK; kk += 4) {
            unsigned long long msk = __ballot(myk == kk);
            int pos = __popcll(msk & ((1ull << lane) - 1ull));
            if (myk == kk) splist[kk][pos] = (unsigned char)lane;
            if (lane == 0) scnt[kk] = __popcll(msk);
        }
    }
    __syncthreads();   // lists ready

    float* pc = pcent + (size_t)(b * 9 + pb) * NK * CSTR;

    // meta: w = count, sx/sy from lists (threads 0..8)
    if (t < NK) {
        int n = scnt[t];
        float sx = 0.f, sy = 0.f;
        for (int i = 0; i < n; ++i) {
            int p = pb * 64 + splist[t][i];
            sx += (float)(p % SGRID);
            sy += (float)(p / SGRID);
        }
        pc[t * CSTR + 768] = sx * COMPF;
        pc[t * CSTR + 769] = sy * COMPF;
        pc[t * CSTR + 770] = (float)n;
    }

    // phase 2: branch-free WTA partial sums; thread t<192 owns channels 4t..4t+3
    if (t < 192) {
        const unsigned short* e2 = eg + 4 * t;
        #pragma unroll
        for (int k = 0; k < NK; ++k) {
            int n = scnt[k];
            float a0 = 0.f, a1 = 0.f, a2 = 0.f, a3 = 0.f;
            for (int i = 0; i < n; ++i) {
                int p = splist[k][i];
                ushort4 u = *(const ushort4*)(e2 + (size_t)p * EMB);
                a0 += b2f(u.x); a1 += b2f(u.y); a2 += b2f(u.z); a3 += b2f(u.w);
            }
            *(float4*)&pc[k * CSTR + t * 4] = make_float4(a0, a1, a2, a3);
        }
    }
}

// ---------------- reduce: 9 partials -> bf16 centroids + csp ----------------
__global__ __launch_bounds__(256) void reduce_k(const float* __restrict__ pcent,
                                                unsigned short* __restrict__ centb,
                                                float* __restrict__ csp) {
    __shared__ float sw[NK];
    int b = blockIdx.x / 3, cb = blockIdx.x % 3;
    int t = threadIdx.x;
    const float* pc = pcent + (size_t)b * 9 * NK * CSTR;

    if (t < NK) {
        float w = 0.f, sx = 0.f, sy = 0.f;
        for (int s = 0; s < 9; ++s) {
            const float* q = pc + (size_t)(s * NK + t) * CSTR;
            sx += q[768]; sy += q[769]; w += q[770];
        }
        float wi = w + EPSV;
        sw[t] = wi;
        if (cb == 0) {
            csp[((size_t)b * NK + t) * 2 + 0] = sx / wi;
            csp[((size_t)b * NK + t) * 2 + 1] = sy / wi;
        }
    }
    __syncthreads();

    int c = cb * 256 + t;
    #pragma unroll
    for (int k = 0; k < NK; ++k) {
        float v = 0.f;
        #pragma unroll
        for (int s = 0; s < 9; ++s) v += pc[(size_t)(s * NK + k) * CSTR + c];
        centb[((size_t)b * NK + k) * EMB + c] = f2b(v / sw[k]);
    }
}

extern "C" void kernel_launch(void* const* d_in, const int* in_sizes, int n_in,
                              void* d_out, int out_size, void* d_ws, size_t ws_size,
                              hipStream_t stream) {
    const float* emb = (const float*)d_in[0];
    char* w = (char*)d_ws;
    unsigned short* embb = (unsigned short*)w;  w += (size_t)NB * NP * EMB * 2;          // 113.2 MB
    float* pcent = (float*)w;                   w += (size_t)NB * 9 * NK * CSTR * 4;     // 32.0 MB
    unsigned short* centb = (unsigned short*)w; w += (size_t)NB * NK * EMB * 2;          // 1.8 MB
    float* csp = (float*)w;                     w += (size_t)NB * NK * 2 * 4;

    init_k<<<NB * 9, 192, 0, stream>>>(emb, embb, pcent);
    reduce_k<<<NB * 3, 256, 0, stream>>>(pcent, centb, csp);

    for (int it = 0; it < NITER; ++it) {
        fused_k<<<NB * 9, 256, 0, stream>>>(embb, centb, csp, pcent, nullptr, 0);
        reduce_k<<<NB * 3, 256, 0, stream>>>(pcent, centb, csp);
    }
    fused_k<<<NB * 9, 256, 0, stream>>>(embb, centb, csp, pcent, (float*)d_out, 1);
}

// Round 6
// 155.619 us; speedup vs baseline: 6.7352x; 4.7752x over previous
//
#include <hip/hip_runtime.h>

#define NB 128
#define NP 576
#define NK 9
#define EMB 768
#define SGRID 24
#define COMPF 3.0f
#define NITER 10
#define EPSV 1e-8f
#define CSTR 772   // per-cluster stride in pcent: 768 ch + sx,sy,w,pad

typedef short v8s __attribute__((ext_vector_type(8)));
typedef float v4f __attribute__((ext_vector_type(4)));

__device__ __forceinline__ unsigned short f2b(float f) {
    unsigned x = __float_as_uint(f);
    unsigned r = (x + 0x7fffu + ((x >> 16) & 1u)) >> 16;
    return (unsigned short)r;
}
__device__ __forceinline__ float b2f(unsigned short u) {
    return __uint_as_float(((unsigned)u) << 16);
}

// ---------------- init: fp32->bf16 conversion + indicator partials ----------
// grid NB*9, 192 thr. Block = one 64-point tile; ay = pb/3 (3 tiles per band).
// Also zeroes the per-item convergence flags (ws is poisoned 0xAA).
__global__ __launch_bounds__(192) void init_k(const float* __restrict__ emb,
                                              unsigned short* __restrict__ embb,
                                              float* __restrict__ pcent,
                                              int* __restrict__ conv,
                                              int* __restrict__ changed) {
    int blk = blockIdx.x, b = blk / 9, pb = blk % 9;
    int t = threadIdx.x;
    int ay = pb / 3;

    if (pb == 0 && t == 0) { conv[b] = 0; changed[b] = 0; }

    float a0x=0,a0y=0,a0z=0,a0w=0, a1x=0,a1y=0,a1z=0,a1w=0, a2x=0,a2y=0,a2z=0,a2w=0;
    const float* eg = emb + ((size_t)b * NP + pb * 64) * EMB + t * 4;
    unsigned short* og = embb + ((size_t)b * NP + pb * 64) * EMB + t * 4;
    for (int p = 0; p < 64; ++p) {
        float4 f = *(const float4*)(eg + (size_t)p * EMB);
        ushort4 u;
        u.x = f2b(f.x); u.y = f2b(f.y); u.z = f2b(f.z); u.w = f2b(f.w);
        *(ushort4*)(og + (size_t)p * EMB) = u;
        int pg = pb * 64 + p;
        int sel = (pg % SGRID) >> 3;   // 0..2
        bool m0 = (sel == 0), m1 = (sel == 1), m2 = (sel == 2);
        a0x += m0 ? f.x : 0.f; a0y += m0 ? f.y : 0.f; a0z += m0 ? f.z : 0.f; a0w += m0 ? f.w : 0.f;
        a1x += m1 ? f.x : 0.f; a1y += m1 ? f.y : 0.f; a1z += m1 ? f.z : 0.f; a1w += m1 ? f.w : 0.f;
        a2x += m2 ? f.x : 0.f; a2y += m2 ? f.y : 0.f; a2z += m2 ? f.z : 0.f; a2w += m2 ? f.w : 0.f;
    }
    float* pc = pcent + (size_t)(b * 9 + pb) * NK * CSTR;
    #pragma unroll
    for (int k = 0; k < NK; ++k) {
        int s = k - ay * 3;
        float4 v = make_float4(0.f, 0.f, 0.f, 0.f);
        if (s == 0) v = make_float4(a0x, a0y, a0z, a0w);
        if (s == 1) v = make_float4(a1x, a1y, a1z, a1w);
        if (s == 2) v = make_float4(a2x, a2y, a2z, a2w);
        *(float4*)&pc[k * CSTR + t * 4] = v;
    }
    if (t < NK) {
        int s = t - ay * 3;
        float w = 0.f, sx = 0.f, sy = 0.f;
        if (s >= 0 && s < 3) {
            for (int p = 0; p < 64; ++p) {
                int pg = pb * 64 + p;
                if (((pg % SGRID) >> 3) == s) {
                    w += 1.f;
                    sx += (float)(pg % SGRID) * COMPF;
                    sy += (float)(pg / SGRID) * COMPF;
                }
            }
        }
        pc[t * CSTR + 768] = sx; pc[t * CSTR + 769] = sy; pc[t * CSTR + 770] = w;
    }
}

// ---------------- fused: MFMA assign + WTA-list partial update ----------------
// grid NB*9, 256 thr (4 waves). Early-exits when the item has converged.
__global__ __launch_bounds__(256) void fused_k(
    const unsigned short* __restrict__ embb,   // [NB][576][768] bf16
    const unsigned short* __restrict__ centb,  // [NB][9][768] bf16
    const float* __restrict__ csp,             // [NB][9][2]
    float* __restrict__ pcent,                 // [NB][9][NK][CSTR]
    unsigned char* __restrict__ prev,          // [NB][NP] last WTA assignment
    int* __restrict__ conv,                    // [NB] converged latch
    int* __restrict__ changed,                 // [NB] per-iteration change flag
    int itFirst,
    float* __restrict__ out, int outMode)
{
    __shared__ unsigned short sc[16][776];     // B: [cluster][768 + pad8]
    __shared__ unsigned short sa[2][64][64];   // A dbuf, slice-swizzled
    __shared__ float scx[16], scy[16], sc2[16];
    __shared__ int swin[64];
    __shared__ int scnt[NK];
    __shared__ unsigned char splist[NK][64];

    int blk = blockIdx.x;
    int b = blk / 9, pb = blk % 9;
    if (!outMode && conv[b] != 0) return;      // item converged: fixed point

    int t = threadIdx.x, lane = t & 63, wv = t >> 6;
    int r16 = lane & 15, g = lane >> 4;

    // stage centroids (B operand), zero-pad clusters 9..15
    const unsigned short* cg = centb + (size_t)b * NK * EMB;
    for (int i = t; i < NK * 96; i += 256) {
        int k = i / 96, s = i % 96;
        *(v8s*)&sc[k][s * 8] = *(const v8s*)&cg[k * EMB + s * 8];
    }
    for (int i = t; i < 7 * 96; i += 256) {
        int k = 9 + i / 96, s = i % 96;
        v8s z = {0,0,0,0,0,0,0,0};
        *(v8s*)&sc[k][s * 8] = z;
    }
    if (t < 16) {
        scx[t] = (t < NK) ? csp[((size_t)b * NK + t) * 2 + 0] : 0.f;
        scy[t] = (t < NK) ? csp[((size_t)b * NK + t) * 2 + 1] : 0.f;
    }

    // first A chunk (issue before the barrier; stored after)
    const unsigned short* eg = embb + ((size_t)b * NP + pb * 64) * EMB;
    int srow = wv * 16 + (lane >> 3);
    int sphys = ((lane & 7) ^ (lane >> 3)) * 8;
    const unsigned short* gbase = eg + (size_t)srow * EMB + (lane & 7) * 8;
    v8s st0 = *(const v8s*)(gbase);
    v8s st1 = *(const v8s*)(gbase + 8 * EMB);

    __syncthreads();   // sc, scx/scy ready

    // c2 from staged bf16 centroids — wave 0
    if (wv == 0) {
        for (int k = 0; k < NK; ++k) {
            float s = 0.f;
            const unsigned short* ck = sc[k];
            for (int c = lane; c < EMB; c += 64) { float v = b2f(ck[c]); s += v * v; }
            #pragma unroll
            for (int m = 1; m < 64; m <<= 1) s += __shfl_xor(s, m);
            if (lane == 0) sc2[k] = s + scx[k] * scx[k] + scy[k] * scy[k];
        }
        if (lane >= NK && lane < 16) sc2[lane] = 1e30f;
    }

    *(v8s*)&sa[0][srow][sphys] = st0;
    *(v8s*)&sa[0][srow + 8][sphys] = st1;

    v4f acc = {0.f, 0.f, 0.f, 0.f};
    for (int cn = 0; cn < 12; ++cn) {
        v8s n0, n1;
        if (cn < 11) {
            n0 = *(const v8s*)(gbase + (cn + 1) * 64);
            n1 = *(const v8s*)(gbase + (cn + 1) * 64 + 8 * EMB);
        }
        __syncthreads();
        int cur = cn & 1;
        #pragma unroll
        for (int ks = 0; ks < 2; ++ks) {
            v8s af = *(const v8s*)&sa[cur][wv * 16 + r16][(((ks << 2) + g) ^ (r16 & 7)) << 3];
            v8s bf = *(const v8s*)&sc[r16][cn * 64 + ks * 32 + g * 8];
            acc = __builtin_amdgcn_mfma_f32_16x16x32_bf16(af, bf, acc, 0, 0, 0);
        }
        if (cn < 11) {
            *(v8s*)&sa[cur ^ 1][srow][sphys] = n0;
            *(v8s*)&sa[cur ^ 1][srow + 8][sphys] = n1;
        }
    }

    // epilogue: C/D layout col=r16, row=g*4+j
    float cxv = scx[r16], cyv = scy[r16], c2v = sc2[r16];
    #pragma unroll
    for (int j = 0; j < 4; ++j) {
        int lr = wv * 16 + g * 4 + j;
        int p = pb * 64 + lr;
        float px = (float)(p % SGRID) * COMPF;
        float py = (float)(p / SGRID) * COMPF;
        float lg = 2.f * (acc[j] + px * cxv + py * cyv) - c2v;
        if (outMode) {
            float mx = lg;
            mx = fmaxf(mx, __shfl_xor(mx, 1));
            mx = fmaxf(mx, __shfl_xor(mx, 2));
            mx = fmaxf(mx, __shfl_xor(mx, 4));
            mx = fmaxf(mx, __shfl_xor(mx, 8));
            float e = __expf(lg - mx);
            float se = e;
            se += __shfl_xor(se, 1);
            se += __shfl_xor(se, 2);
            se += __shfl_xor(se, 4);
            se += __shfl_xor(se, 8);
            if (r16 < NK) out[((size_t)b * NP + p) * NK + r16] = e / se;
        } else {
            float m = lg; int ki = r16;
            #pragma unroll
            for (int d = 1; d < 16; d <<= 1) {
                float om = __shfl_xor(m, d);
                int oi = __shfl_xor(ki, d);
                if (om > m || (om == m && oi < ki)) { m = om; ki = oi; }
            }
            if (r16 == 0) swin[lr] = ki;
        }
    }
    if (outMode) return;
    __syncthreads();   // swin complete

    // convergence tracking (wave 1) + per-cluster list building (all waves)
    if (wv == 1) {
        unsigned char* prevb = prev + (size_t)b * NP + pb * 64;
        unsigned char neww = (unsigned char)swin[lane];
        bool diff = itFirst ? true : (prevb[lane] != neww);
        prevb[lane] = neww;
        unsigned long long m = __ballot(diff);
        if (lane == 0 && m != 0ull) changed[b] = 1;
    }
    {
        int myk = swin[lane];
        for (int kk = wv; kk < NK; kk += 4) {
            unsigned long long msk = __ballot(myk == kk);
            int pos = __popcll(msk & ((1ull << lane) - 1ull));
            if (myk == kk) splist[kk][pos] = (unsigned char)lane;
            if (lane == 0) scnt[kk] = __popcll(msk);
        }
    }
    __syncthreads();   // lists ready

    float* pc = pcent + (size_t)(b * 9 + pb) * NK * CSTR;

    // meta: w = count, sx/sy from lists (threads 0..8)
    if (t < NK) {
        int n = scnt[t];
        float sx = 0.f, sy = 0.f;
        for (int i = 0; i < n; ++i) {
            int p = pb * 64 + splist[t][i];
            sx += (float)(p % SGRID);
            sy += (float)(p / SGRID);
        }
        pc[t * CSTR + 768] = sx * COMPF;
        pc[t * CSTR + 769] = sy * COMPF;
        pc[t * CSTR + 770] = (float)n;
    }

    // phase 2: branch-free WTA partial sums; thread t<192 owns channels 4t..4t+3
    if (t < 192) {
        const unsigned short* e2 = eg + 4 * t;
        #pragma unroll
        for (int k = 0; k < NK; ++k) {
            int n = scnt[k];
            float a0 = 0.f, a1 = 0.f, a2 = 0.f, a3 = 0.f;
            for (int i = 0; i < n; ++i) {
                int p = splist[k][i];
                ushort4 u = *(const ushort4*)(e2 + (size_t)p * EMB);
                a0 += b2f(u.x); a1 += b2f(u.y); a2 += b2f(u.z); a3 += b2f(u.w);
            }
            *(float4*)&pc[k * CSTR + t * 4] = make_float4(a0, a1, a2, a3);
        }
    }
}

// ---------------- reduce: 9 partials -> bf16 centroids + csp ----------------
__global__ __launch_bounds__(256) void reduce_k(const float* __restrict__ pcent,
                                                unsigned short* __restrict__ centb,
                                                float* __restrict__ csp,
                                                int* __restrict__ conv,
                                                int* __restrict__ changed) {
    __shared__ float sw[NK];
    int b = blockIdx.x / 3, cb = blockIdx.x % 3;
    if (conv[b] != 0) return;                  // fixed point: centb/csp already valid
    int t = threadIdx.x;
    const float* pc = pcent + (size_t)b * 9 * NK * CSTR;

    if (t < NK) {
        float w = 0.f, sx = 0.f, sy = 0.f;
        for (int s = 0; s < 9; ++s) {
            const float* q = pc + (size_t)(s * NK + t) * CSTR;
            sx += q[768]; sy += q[769]; w += q[770];
        }
        float wi = w + EPSV;
        sw[t] = wi;
        if (cb == 0) {
            csp[((size_t)b * NK + t) * 2 + 0] = sx / wi;
            csp[((size_t)b * NK + t) * 2 + 1] = sy / wi;
        }
    }
    __syncthreads();

    int c = cb * 256 + t;
    #pragma unroll
    for (int k = 0; k < NK; ++k) {
        float v = 0.f;
        #pragma unroll
        for (int s = 0; s < 9; ++s) v += pc[(size_t)(s * NK + k) * CSTR + c];
        centb[((size_t)b * NK + k) * EMB + c] = f2b(v / sw[k]);
    }

    // convergence latch: if this iteration changed nothing, freeze the item
    if (cb == 0 && t == 0) {
        if (changed[b] == 0) conv[b] = 1;
        changed[b] = 0;
    }
}

extern "C" void kernel_launch(void* const* d_in, const int* in_sizes, int n_in,
                              void* d_out, int out_size, void* d_ws, size_t ws_size,
                              hipStream_t stream) {
    const float* emb = (const float*)d_in[0];
    char* w = (char*)d_ws;
    unsigned short* embb = (unsigned short*)w;  w += (size_t)NB * NP * EMB * 2;          // 113.2 MB
    float* pcent = (float*)w;                   w += (size_t)NB * 9 * NK * CSTR * 4;     // 32.0 MB
    unsigned short* centb = (unsigned short*)w; w += (size_t)NB * NK * EMB * 2;          // 1.8 MB
    float* csp = (float*)w;                     w += (size_t)NB * NK * 2 * 4;
    unsigned char* prev = (unsigned char*)w;    w += (size_t)NB * NP;                    // 72 KB
    int* conv = (int*)w;                        w += (size_t)NB * 4;
    int* changed = (int*)w;                     w += (size_t)NB * 4;

    init_k<<<NB * 9, 192, 0, stream>>>(emb, embb, pcent, conv, changed);
    reduce_k<<<NB * 3, 256, 0, stream>>>(pcent, centb, csp, conv, changed);

    for (int it = 0; it < NITER; ++it) {
        fused_k<<<NB * 9, 256, 0, stream>>>(embb, centb, csp, pcent, prev, conv, changed,
                                            (it == 0) ? 1 : 0, nullptr, 0);
        reduce_k<<<NB * 3, 256, 0, stream>>>(pcent, centb, csp, conv, changed);
    }
    fused_k<<<NB * 9, 256, 0, stream>>>(embb, centb, csp, pcent, prev, conv, changed,
                                        0, (float*)d_out, 1);
}